// Round 1
// baseline (187.004 us; speedup 1.0000x reference)
//
#include <hip/hip_runtime.h>
#include <cfloat>

// ECE: N=1e6 rows, C=100 fp32 logits, int32 labels, 15 bins.
// Kernel 1: per-row max/argmax (4 lanes/row, float4 loads), per-block LDS bin
//           accumulation, per-block partials -> d_ws.
// Kernel 2: reduce partials, compute (ece*100, acc*100) -> d_out[0..1].

#define ECE_NBINS 15
#define ECE_NSTATS 45   // count[15], sum_acc[15], sum_conf[15]

__global__ __launch_bounds__(256) void ece_partial_kernel(
    const float* __restrict__ logits, const int* __restrict__ labels,
    float* __restrict__ ws, int n_rows, int G, int tiles)
{
    __shared__ float s_stats[ECE_NSTATS];
    const int tid = threadIdx.x;
    if (tid < ECE_NSTATS) s_stats[tid] = 0.0f;
    __syncthreads();

    const int sub  = tid & 3;   // lane within 4-lane row group
    const int lrow = tid >> 2;  // 0..63 local row

    for (int tile = blockIdx.x; tile < tiles; tile += G) {
        const int r = tile * 64 + lrow;
        if (r < n_rows) {
            const float4* rowp = (const float4*)(logits + (size_t)r * 100);
            float best = -FLT_MAX;
            int   bidx = 0;
            // 25 float4 per row; lane `sub` takes indices sub, sub+4, ...
            // strict > keeps first occurrence within this lane's subset.
            #pragma unroll 7
            for (int j = sub; j < 25; j += 4) {
                const float4 v = rowp[j];
                const int e = j * 4;
                if (v.x > best) { best = v.x; bidx = e;     }
                if (v.y > best) { best = v.y; bidx = e + 1; }
                if (v.z > best) { best = v.z; bidx = e + 2; }
                if (v.w > best) { best = v.w; bidx = e + 3; }
            }
            // combine across the 4 lanes of this row; tie -> lower index
            #pragma unroll
            for (int m = 1; m <= 2; m <<= 1) {
                const float ov = __shfl_xor(best, m);
                const int   oi = __shfl_xor(bidx, m);
                if (ov > best || (ov == best && oi < bidx)) { best = ov; bidx = oi; }
            }
            if (sub == 0) {
                const float accv = (bidx == labels[r]) ? 1.0f : 0.0f;
                int bin = (int)ceilf(best * 15.0f) - 1;   // lower < c <= upper
                bin = bin < 0 ? 0 : (bin > 14 ? 14 : bin);
                atomicAdd(&s_stats[bin],      1.0f);
                atomicAdd(&s_stats[15 + bin], accv);
                atomicAdd(&s_stats[30 + bin], best);
            }
        }
    }
    __syncthreads();
    if (tid < ECE_NSTATS) ws[(size_t)tid * G + blockIdx.x] = s_stats[tid];
}

__global__ __launch_bounds__(256) void ece_final_kernel(
    const float* __restrict__ ws, float* __restrict__ out, int G, float n_total)
{
    __shared__ float s_sum[ECE_NSTATS];
    const int tid  = threadIdx.x;
    const int wave = tid >> 6;
    const int lane = tid & 63;

    for (int s = wave; s < ECE_NSTATS; s += 4) {
        float v = 0.0f;
        for (int j = lane; j < G; j += 64) v += ws[(size_t)s * G + j];
        #pragma unroll
        for (int m = 32; m >= 1; m >>= 1) v += __shfl_xor(v, m);
        if (lane == 0) s_sum[s] = v;
    }
    __syncthreads();

    if (tid == 0) {
        float ece = 0.0f, acc = 0.0f;
        #pragma unroll
        for (int b = 0; b < ECE_NBINS; ++b) {
            const float cnt = s_sum[b];
            if (cnt > 0.0f) {
                const float prop = cnt / n_total;
                const float a = s_sum[15 + b] / cnt;
                const float c = s_sum[30 + b] / cnt;
                ece += fabsf(c - a) * prop;
                acc += a * prop;
            }
        }
        out[0] = ece * 100.0f;
        out[1] = acc * 100.0f;
    }
}

extern "C" void kernel_launch(void* const* d_in, const int* in_sizes, int n_in,
                              void* d_out, int out_size, void* d_ws, size_t ws_size,
                              hipStream_t stream) {
    const float* logits = (const float*)d_in[0];
    const int*   labels = (const int*)d_in[1];
    float*       out    = (float*)d_out;
    float*       ws     = (float*)d_ws;

    const int n_rows = in_sizes[1];              // N = 1,000,000 (labels count)
    const int tiles  = (n_rows + 63) / 64;       // 64 rows per block-tile

    int G = 2048;                                 // 8 blocks/CU on 256 CUs
    const size_t maxG = ws_size / (ECE_NSTATS * sizeof(float));
    if ((size_t)G > maxG) G = (int)maxG;
    if (G > tiles) G = tiles;
    if (G < 1) G = 1;

    ece_partial_kernel<<<G, 256, 0, stream>>>(logits, labels, ws, n_rows, G, tiles);
    ece_final_kernel<<<1, 256, 0, stream>>>((const float*)ws, out, G, (float)n_rows);
}

// Round 2
// 79.546 us; speedup vs baseline: 2.3509x; 2.3509x over previous
//
#include <hip/hip_runtime.h>
#include <cfloat>

// ECE: N=1e6 rows, C=100 fp32 logits, int32 labels, 15 bins.
// K1: per-row max/argmax (4 lanes/row, float4 loads), per-block LDS bin
//     accumulation, per-block partials -> ws[s*G + block].
// K2: 45 blocks, block s reduces ws[s*G..s*G+G) -> red[s]  (coalesced).
// K3: 1 wave finalizes (ece*100, acc*100) -> d_out[0..1].

#define ECE_NBINS 15
#define ECE_NSTATS 45   // count[15], sum_acc[15], sum_conf[15]

__global__ __launch_bounds__(256) void ece_partial_kernel(
    const float* __restrict__ logits, const int* __restrict__ labels,
    float* __restrict__ ws, int n_rows, int G, int tiles)
{
    __shared__ float s_stats[ECE_NSTATS];
    const int tid = threadIdx.x;
    if (tid < ECE_NSTATS) s_stats[tid] = 0.0f;
    __syncthreads();

    const int sub  = tid & 3;   // lane within 4-lane row group
    const int lrow = tid >> 2;  // 0..63 local row

    for (int tile = blockIdx.x; tile < tiles; tile += G) {
        const int r = tile * 64 + lrow;
        if (r < n_rows) {
            const float4* rowp = (const float4*)(logits + (size_t)r * 100);
            float best = -FLT_MAX;
            int   bidx = 0;
            // 25 float4 per row; lane `sub` takes indices sub, sub+4, ...
            // strict > keeps first occurrence within this lane's subset.
            #pragma unroll 7
            for (int j = sub; j < 25; j += 4) {
                const float4 v = rowp[j];
                const int e = j * 4;
                if (v.x > best) { best = v.x; bidx = e;     }
                if (v.y > best) { best = v.y; bidx = e + 1; }
                if (v.z > best) { best = v.z; bidx = e + 2; }
                if (v.w > best) { best = v.w; bidx = e + 3; }
            }
            // combine across the 4 lanes of this row; tie -> lower index
            #pragma unroll
            for (int m = 1; m <= 2; m <<= 1) {
                const float ov = __shfl_xor(best, m);
                const int   oi = __shfl_xor(bidx, m);
                if (ov > best || (ov == best && oi < bidx)) { best = ov; bidx = oi; }
            }
            if (sub == 0) {
                const float accv = (bidx == labels[r]) ? 1.0f : 0.0f;
                int bin = (int)ceilf(best * 15.0f) - 1;   // lower < c <= upper
                bin = bin < 0 ? 0 : (bin > 14 ? 14 : bin);
                atomicAdd(&s_stats[bin],      1.0f);
                atomicAdd(&s_stats[15 + bin], accv);
                atomicAdd(&s_stats[30 + bin], best);
            }
        }
    }
    __syncthreads();
    if (tid < ECE_NSTATS) ws[(size_t)tid * G + blockIdx.x] = s_stats[tid];
}

// Block s sums ws[s*G .. s*G+G) -> red[s]. Coalesced, 45 blocks in parallel.
__global__ __launch_bounds__(256) void ece_reduce_kernel(
    const float* __restrict__ ws, float* __restrict__ red, int G)
{
    const int s = blockIdx.x;
    const float* p = ws + (size_t)s * G;
    float v = 0.0f;
    for (int j = threadIdx.x; j < G; j += 256) v += p[j];

    __shared__ float sw[4];
    #pragma unroll
    for (int m = 32; m >= 1; m >>= 1) v += __shfl_xor(v, m);
    if ((threadIdx.x & 63) == 0) sw[threadIdx.x >> 6] = v;
    __syncthreads();
    if (threadIdx.x == 0) red[s] = sw[0] + sw[1] + sw[2] + sw[3];
}

__global__ __launch_bounds__(64) void ece_finalize_kernel(
    const float* __restrict__ red, float* __restrict__ out, float n_total)
{
    const int lane = threadIdx.x;
    float ece = 0.0f, acc = 0.0f;
    if (lane < ECE_NBINS) {
        const float cnt = red[lane];
        if (cnt > 0.0f) {
            const float prop = cnt / n_total;
            const float a = red[15 + lane] / cnt;
            const float c = red[30 + lane] / cnt;
            ece = fabsf(c - a) * prop;
            acc = a * prop;
        }
    }
    #pragma unroll
    for (int m = 32; m >= 1; m >>= 1) {
        ece += __shfl_xor(ece, m);
        acc += __shfl_xor(acc, m);
    }
    if (lane == 0) {
        out[0] = ece * 100.0f;
        out[1] = acc * 100.0f;
    }
}

extern "C" void kernel_launch(void* const* d_in, const int* in_sizes, int n_in,
                              void* d_out, int out_size, void* d_ws, size_t ws_size,
                              hipStream_t stream) {
    const float* logits = (const float*)d_in[0];
    const int*   labels = (const int*)d_in[1];
    float*       out    = (float*)d_out;
    float*       ws     = (float*)d_ws;

    const int n_rows = in_sizes[1];              // N = 1,000,000 (labels count)
    const int tiles  = (n_rows + 63) / 64;       // 64 rows per block-tile

    int G = 2048;                                 // 8 blocks/CU on 256 CUs
    const size_t maxG = (ws_size / sizeof(float) - ECE_NSTATS) / ECE_NSTATS;
    if ((size_t)G > maxG) G = (int)maxG;
    if (G > tiles) G = tiles;
    if (G < 1) G = 1;

    float* red = ws + (size_t)ECE_NSTATS * G;    // 45 reduced stats

    ece_partial_kernel<<<G, 256, 0, stream>>>(logits, labels, ws, n_rows, G, tiles);
    ece_reduce_kernel<<<ECE_NSTATS, 256, 0, stream>>>((const float*)ws, red, G);
    ece_finalize_kernel<<<1, 64, 0, stream>>>((const float*)red, out, (float)n_rows);
}